// Round 4
// baseline (257.307 us; speedup 1.0000x reference)
//
#include <hip/hip_runtime.h>

// SNN_60567628808223: 2-layer LIF SNN.
//   inputs: data[16384,784] f32, W1[128,784], b1[128], W2[10,128], b2[10]
//   output: spk2 [50,16384,10] f32 (binary 0/1)
//
// CORRECTNESS INVARIANT (learned R2/R3): output = 8.2M binary threshold
// decisions; ulp-level summation-order changes flip spikes. Round-1 bits
// pass (absmax 0.0). Therefore:
//   - cur1: each element MUST be the ascending-k single fmaf chain
//     acc = fmaf(data[m][k], W1[n][k], acc), k = 0..783, then one +bias.
//     (Tiling/staging may change freely; the chain may not.)
//   - snn_loop: byte-for-byte round-1 arithmetic.
//
// R4 change: gemm_cur1 8x8 micro-tile (was 4x4). Round-1 was LDS-bound
// (2 B/FMA vs 0.66 sustainable); 8x8 gives 1 B/FMA -> VALU-bound.
// BM=64 x BN=128(all of N), 128 threads, grid=256 (1 block/CU, 2 waves/CU).
// cur1 is BIT-IDENTICAL to round 1.

#define TSTEPS 50
#define NB 16384
#define ND 784
#define NH 128
#define NO 10

// ---------------- Phase A: exact fp32 GEMM, 8x8 micro ----------------
__global__ __launch_bounds__(128)
void gemm_cur1(const float* __restrict__ data, const float* __restrict__ W1,
               const float* __restrict__ b1, float* __restrict__ cur1)
{
    __shared__ float As[16][64];    // As[k][m] = data[row0+m][c*16+k]
    __shared__ float Ws[16][128];   // Ws[k][n] = W1[n][c*16+k]

    const int tid  = threadIdx.x;
    const int row0 = blockIdx.x * 64;

    // staging: A -> thread (lmA = tid>>1 row, lkA = (tid&1)*8 k-half), 8 floats
    //          B -> thread tid = row n, 16 floats (whole k-chunk)
    const int lmA = tid >> 1;
    const int lkA = (tid & 1) * 8;
    const float* aSrc = data + (size_t)(row0 + lmA) * ND + lkA;
    const float* wSrc = W1   + (size_t)tid * ND;

    // compute: thread (tm = tid>>4 owns 8 rows, tn = tid&15 owns 8 cols)
    const int tm = tid >> 4;
    const int tn = tid & 15;

    float4 a0 = *(const float4*)(aSrc);
    float4 a1 = *(const float4*)(aSrc + 4);
    float4 w0 = *(const float4*)(wSrc);
    float4 w1 = *(const float4*)(wSrc + 4);
    float4 w2 = *(const float4*)(wSrc + 8);
    float4 w3 = *(const float4*)(wSrc + 12);

    float acc[8][8] = {};

    for (int c = 0; c < 49; ++c) {
        __syncthreads();
        As[lkA + 0][lmA] = a0.x;  As[lkA + 1][lmA] = a0.y;
        As[lkA + 2][lmA] = a0.z;  As[lkA + 3][lmA] = a0.w;
        As[lkA + 4][lmA] = a1.x;  As[lkA + 5][lmA] = a1.y;
        As[lkA + 6][lmA] = a1.z;  As[lkA + 7][lmA] = a1.w;
        Ws[ 0][tid] = w0.x;  Ws[ 1][tid] = w0.y;
        Ws[ 2][tid] = w0.z;  Ws[ 3][tid] = w0.w;
        Ws[ 4][tid] = w1.x;  Ws[ 5][tid] = w1.y;
        Ws[ 6][tid] = w1.z;  Ws[ 7][tid] = w1.w;
        Ws[ 8][tid] = w2.x;  Ws[ 9][tid] = w2.y;
        Ws[10][tid] = w2.z;  Ws[11][tid] = w2.w;
        Ws[12][tid] = w3.x;  Ws[13][tid] = w3.y;
        Ws[14][tid] = w3.z;  Ws[15][tid] = w3.w;
        __syncthreads();
        if (c < 48) {   // prefetch next chunk into registers (overlaps compute)
            const int off = (c + 1) * 16;
            a0 = *(const float4*)(aSrc + off);
            a1 = *(const float4*)(aSrc + off + 4);
            w0 = *(const float4*)(wSrc + off);
            w1 = *(const float4*)(wSrc + off + 4);
            w2 = *(const float4*)(wSrc + off + 8);
            w3 = *(const float4*)(wSrc + off + 12);
        }
        #pragma unroll
        for (int k = 0; k < 16; ++k) {
            float4 av0 = *(const float4*)&As[k][tm * 8];
            float4 av1 = *(const float4*)&As[k][tm * 8 + 4];
            float4 bv0 = *(const float4*)&Ws[k][tn * 8];
            float4 bv1 = *(const float4*)&Ws[k][tn * 8 + 4];
            float av[8] = {av0.x, av0.y, av0.z, av0.w, av1.x, av1.y, av1.z, av1.w};
            float bv[8] = {bv0.x, bv0.y, bv0.z, bv0.w, bv1.x, bv1.y, bv1.z, bv1.w};
            #pragma unroll
            for (int i = 0; i < 8; ++i)
                #pragma unroll
                for (int j = 0; j < 8; ++j)
                    acc[i][j] = fmaf(av[i], bv[j], acc[i][j]);
        }
    }

    // epilogue: one fadd of bias per element (same op as round 1), float4 stores
    const float* bp = b1 + tn * 8;
    float bias[8] = {bp[0], bp[1], bp[2], bp[3], bp[4], bp[5], bp[6], bp[7]};
    #pragma unroll
    for (int i = 0; i < 8; ++i) {
        const size_t rowOff = (size_t)(row0 + tm * 8 + i) * NH + tn * 8;
        float4 o0, o1;
        o0.x = acc[i][0] + bias[0];
        o0.y = acc[i][1] + bias[1];
        o0.z = acc[i][2] + bias[2];
        o0.w = acc[i][3] + bias[3];
        o1.x = acc[i][4] + bias[4];
        o1.y = acc[i][5] + bias[5];
        o1.z = acc[i][6] + bias[6];
        o1.w = acc[i][7] + bias[7];
        *(float4*)&cur1[rowOff]     = o0;
        *(float4*)&cur1[rowOff + 4] = o1;
    }
}

// ---------------- Phase B: round-1 fused time loop, VERBATIM ----------------
// 16 lanes per batch row (8 h each), 16 rows per 256-thread block.
__global__ void snn_loop(const float* __restrict__ cur1,
                         const float* __restrict__ W2,
                         const float* __restrict__ b2,
                         float* __restrict__ out)
{
    const int tid = threadIdx.x;
    const int hg  = tid & 15;
    const int rl  = tid >> 4;
    const int row = blockIdx.x * 16 + rl;
    const int h0  = hg * 8;

    float w2[10][8];
    #pragma unroll
    for (int o = 0; o < 10; ++o) {
        float4 u = *(const float4*)&W2[o * NH + h0];
        float4 v = *(const float4*)&W2[o * NH + h0 + 4];
        w2[o][0] = u.x; w2[o][1] = u.y; w2[o][2] = u.z; w2[o][3] = u.w;
        w2[o][4] = v.x; w2[o][5] = v.y; w2[o][6] = v.z; w2[o][7] = v.w;
    }
    const float b2r = b2[hg < 10 ? hg : 0];

    float c[8];
    {
        float4 c0 = *(const float4*)&cur1[(size_t)row * NH + h0];
        float4 c1 = *(const float4*)&cur1[(size_t)row * NH + h0 + 4];
        c[0] = c0.x; c[1] = c0.y; c[2] = c0.z; c[3] = c0.w;
        c[4] = c1.x; c[5] = c1.y; c[6] = c1.z; c[7] = c1.w;
    }

    float mem1[8], spk1[8];
    #pragma unroll
    for (int j = 0; j < 8; ++j) { mem1[j] = 0.f; spk1[j] = 0.f; }
    float mem2 = 0.f, spk2 = 0.f;

    for (int t = 0; t < TSTEPS; ++t) {
        #pragma unroll
        for (int j = 0; j < 8; ++j) {
            float m = __fadd_rn(__fmul_rn(0.9f, mem1[j]), c[j]);
            m = __fsub_rn(m, spk1[j]);
            mem1[j] = m;
            spk1[j] = (m > 1.0f) ? 1.0f : 0.0f;
        }
        float p[10];
        #pragma unroll
        for (int o = 0; o < 10; ++o) p[o] = 0.f;
        #pragma unroll
        for (int j = 0; j < 8; ++j)
            #pragma unroll
            for (int o = 0; o < 10; ++o)
                p[o] = fmaf(spk1[j], w2[o][j], p[o]);
        #pragma unroll
        for (int m = 1; m <= 8; m <<= 1)
            #pragma unroll
            for (int o = 0; o < 10; ++o)
                p[o] += __shfl_xor(p[o], m, 64);
        float tot = p[0];
        #pragma unroll
        for (int o = 1; o < 10; ++o)
            tot = (hg == o) ? p[o] : tot;
        float cur2 = __fadd_rn(tot, b2r);
        float m2 = __fsub_rn(__fadd_rn(__fmul_rn(0.9f, mem2), cur2), spk2);
        mem2 = m2;
        spk2 = (m2 > 1.0f) ? 1.0f : 0.0f;
        if (hg < 10)
            out[(size_t)t * (NB * NO) + row * NO + hg] = spk2;
    }
}

extern "C" void kernel_launch(void* const* d_in, const int* in_sizes, int n_in,
                              void* d_out, int out_size, void* d_ws, size_t ws_size,
                              hipStream_t stream) {
    const float* data = (const float*)d_in[0];
    const float* W1   = (const float*)d_in[1];
    const float* b1   = (const float*)d_in[2];
    const float* W2   = (const float*)d_in[3];
    const float* b2   = (const float*)d_in[4];
    float* out  = (float*)d_out;
    float* cur1 = (float*)d_ws;   // 16384*128*4 = 8.4 MB scratch

    gemm_cur1<<<256, 128, 0, stream>>>(data, W1, b1, cur1);
    snn_loop<<<1024, 256, 0, stream>>>(cur1, W2, b2, out);
}

// Round 5
// 252.385 us; speedup vs baseline: 1.0195x; 1.0195x over previous
//
#include <hip/hip_runtime.h>

// SNN_60567628808223: 2-layer LIF SNN.
//   inputs: data[16384,784] f32, W1[128,784], b1[128], W2[10,128], b2[10]
//   output: spk2 [50,16384,10] f32 (binary 0/1)
//
// CORRECTNESS INVARIANT (R2/R3): output = 8.2M binary threshold decisions;
// ulp-level reassociation flips spikes. Round-1 bits pass (absmax 0.0).
//   - cur1[m][n]: ascending-k single fmaf chain + one bias fadd. FROZEN.
//   - snn_loop: round-1 value graph FROZEN (incl. 8-j fmaf chain and the
//     1,2,4,8 butterfly tree). Only the data-MOVEMENT instructions may change.
//
// R5 changes (both bit-exact):
//  1) gemm_cur1: zero-LDS register GEMM. W1 pre-transposed (bit-copy) to
//     Wt[k][n] so B loads are wave-coalesced; A loads use 16-way lane
//     broadcast through L1. R1/R4 were LDS-pipe-bound (both operands from
//     LDS needs 2 B/FMA vs ~85-128 B/cyc/CU) -- this removes LDS entirely.
//  2) snn_loop: butterfly xor1/xor2/xor8 moved from DS pipe to VALU DPP
//     (quad_perm 0xB1 / 0x4E, row_ror:8) -- same exchange pairs, same add
//     tree, bit-identical. xor4 stays ds_swizzle(0x101F). DS-pipe load/t
//     drops 40 -> 10 exchanges.

#define TSTEPS 50
#define NB 16384
#define ND 784
#define NH 128
#define NO 10

// ---------------- W1 bit-copy transpose: Wt[k][n] = W1[n][k] ----------------
__global__ void w1_transpose(const float* __restrict__ W1, float* __restrict__ Wt)
{
    const int k = blockIdx.x;      // 0..783
    const int n = threadIdx.x;     // 0..127
    Wt[k * NH + n] = W1[n * ND + k];
}

// ---------------- Phase A: exact fp32 GEMM, zero LDS ----------------
// grid 512 (bm 0..255 x bn 0..1), 256 threads, 4x4 micro-tile.
// Thread (ty=tid>>4 rows, tn=tid&15 cols): rows row0+ty*4.., cols col0+tn*4..
__global__ __launch_bounds__(256)
void gemm_cur1(const float* __restrict__ data, const float* __restrict__ Wt,
               const float* __restrict__ b1, float* __restrict__ cur1)
{
    const int tid  = threadIdx.x;
    const int bm   = blockIdx.x >> 1;
    const int bn   = blockIdx.x & 1;
    const int row0 = bm * 64;
    const int col0 = bn * 64;
    const int ty   = tid >> 4;
    const int tn   = tid & 15;

    const float* aP0 = data + (size_t)(row0 + ty * 4 + 0) * ND;
    const float* aP1 = data + (size_t)(row0 + ty * 4 + 1) * ND;
    const float* aP2 = data + (size_t)(row0 + ty * 4 + 2) * ND;
    const float* aP3 = data + (size_t)(row0 + ty * 4 + 3) * ND;
    const float* bP  = Wt + col0 + tn * 4;   // + k*NH

    float acc[4][4] = {};

    float4 aCur[4], bCur[4];
    aCur[0] = *(const float4*)(aP0);
    aCur[1] = *(const float4*)(aP1);
    aCur[2] = *(const float4*)(aP2);
    aCur[3] = *(const float4*)(aP3);
    bCur[0] = *(const float4*)(bP + 0 * NH);
    bCur[1] = *(const float4*)(bP + 1 * NH);
    bCur[2] = *(const float4*)(bP + 2 * NH);
    bCur[3] = *(const float4*)(bP + 3 * NH);

    for (int c = 0; c < 196; ++c) {          // 196 float4 chunks over k=784
        float4 aNxt[4], bNxt[4];
        if (c < 195) {
            const int k4 = (c + 1) * 4;
            aNxt[0] = *(const float4*)(aP0 + k4);
            aNxt[1] = *(const float4*)(aP1 + k4);
            aNxt[2] = *(const float4*)(aP2 + k4);
            aNxt[3] = *(const float4*)(aP3 + k4);
            bNxt[0] = *(const float4*)(bP + (size_t)(k4 + 0) * NH);
            bNxt[1] = *(const float4*)(bP + (size_t)(k4 + 1) * NH);
            bNxt[2] = *(const float4*)(bP + (size_t)(k4 + 2) * NH);
            bNxt[3] = *(const float4*)(bP + (size_t)(k4 + 3) * NH);
        }
        // 4 k-steps, ascending; per (i,j): acc = fmaf(a_k[i], b_k[j], acc)
        #pragma unroll
        for (int kk = 0; kk < 4; ++kk) {
            float a[4] = { ((const float*)&aCur[0])[kk],
                           ((const float*)&aCur[1])[kk],
                           ((const float*)&aCur[2])[kk],
                           ((const float*)&aCur[3])[kk] };
            float b[4] = { ((const float*)&bCur[kk])[0],
                           ((const float*)&bCur[kk])[1],
                           ((const float*)&bCur[kk])[2],
                           ((const float*)&bCur[kk])[3] };
            #pragma unroll
            for (int i = 0; i < 4; ++i)
                #pragma unroll
                for (int j = 0; j < 4; ++j)
                    acc[i][j] = fmaf(a[i], b[j], acc[i][j]);
        }
        #pragma unroll
        for (int q = 0; q < 4; ++q) { aCur[q] = aNxt[q]; bCur[q] = bNxt[q]; }
    }

    float4 bv1 = *(const float4*)&b1[col0 + tn * 4];
    #pragma unroll
    for (int i = 0; i < 4; ++i) {
        float4 o;
        o.x = acc[i][0] + bv1.x;
        o.y = acc[i][1] + bv1.y;
        o.z = acc[i][2] + bv1.z;
        o.w = acc[i][3] + bv1.w;
        *(float4*)&cur1[(size_t)(row0 + ty * 4 + i) * NH + col0 + tn * 4] = o;
    }
}

// ---------------- Phase B: round-1 time loop, DPP-accelerated reduce --------
// 16 lanes per batch row (8 h each), 16 rows per 256-thread block.
// Rows-of-16 lanes align with DPP rows. Exchange pairs & add tree are
// IDENTICAL to round-1's __shfl_xor butterfly (m = 1,2,4,8) -- bit-exact.
__device__ __forceinline__ float xmove_dpp_b1(float v) {   // lane ^ 1
    return __int_as_float(__builtin_amdgcn_update_dpp(
        0, __float_as_int(v), 0xB1, 0xF, 0xF, true));      // quad_perm [1,0,3,2]
}
__device__ __forceinline__ float xmove_dpp_b2(float v) {   // lane ^ 2
    return __int_as_float(__builtin_amdgcn_update_dpp(
        0, __float_as_int(v), 0x4E, 0xF, 0xF, true));      // quad_perm [2,3,0,1]
}
__device__ __forceinline__ float xmove_dpp_b8(float v) {   // lane ^ 8 (ror 8 in row16)
    return __int_as_float(__builtin_amdgcn_update_dpp(
        0, __float_as_int(v), 0x128, 0xF, 0xF, true));     // row_ror:8
}
__device__ __forceinline__ float xmove_swz_b4(float v) {   // lane ^ 4
    return __int_as_float(__builtin_amdgcn_ds_swizzle(
        __float_as_int(v), 0x101F));                        // xor-mask 4
}

__global__ void snn_loop(const float* __restrict__ cur1,
                         const float* __restrict__ W2,
                         const float* __restrict__ b2,
                         float* __restrict__ out)
{
    const int tid = threadIdx.x;
    const int hg  = tid & 15;
    const int rl  = tid >> 4;
    const int row = blockIdx.x * 16 + rl;
    const int h0  = hg * 8;

    float w2[10][8];
    #pragma unroll
    for (int o = 0; o < 10; ++o) {
        float4 u = *(const float4*)&W2[o * NH + h0];
        float4 v = *(const float4*)&W2[o * NH + h0 + 4];
        w2[o][0] = u.x; w2[o][1] = u.y; w2[o][2] = u.z; w2[o][3] = u.w;
        w2[o][4] = v.x; w2[o][5] = v.y; w2[o][6] = v.z; w2[o][7] = v.w;
    }
    const float b2r = b2[hg < 10 ? hg : 0];

    float c[8];
    {
        float4 c0 = *(const float4*)&cur1[(size_t)row * NH + h0];
        float4 c1 = *(const float4*)&cur1[(size_t)row * NH + h0 + 4];
        c[0] = c0.x; c[1] = c0.y; c[2] = c0.z; c[3] = c0.w;
        c[4] = c1.x; c[5] = c1.y; c[6] = c1.z; c[7] = c1.w;
    }

    float mem1[8], spk1[8];
    #pragma unroll
    for (int j = 0; j < 8; ++j) { mem1[j] = 0.f; spk1[j] = 0.f; }
    float mem2 = 0.f, spk2 = 0.f;

    for (int t = 0; t < TSTEPS; ++t) {
        #pragma unroll
        for (int j = 0; j < 8; ++j) {
            float m = __fadd_rn(__fmul_rn(0.9f, mem1[j]), c[j]);
            m = __fsub_rn(m, spk1[j]);
            mem1[j] = m;
            spk1[j] = (m > 1.0f) ? 1.0f : 0.0f;
        }
        float p[10];
        #pragma unroll
        for (int o = 0; o < 10; ++o) p[o] = 0.f;
        #pragma unroll
        for (int j = 0; j < 8; ++j)
            #pragma unroll
            for (int o = 0; o < 10; ++o)
                p[o] = fmaf(spk1[j], w2[o][j], p[o]);
        // butterfly m=1,2,4,8 -- same pairs/tree as round-1 __shfl_xor,
        // transported via DPP (VALU) for 1,2,8 and ds_swizzle for 4.
        #pragma unroll
        for (int o = 0; o < 10; ++o) p[o] += xmove_dpp_b1(p[o]);
        #pragma unroll
        for (int o = 0; o < 10; ++o) p[o] += xmove_dpp_b2(p[o]);
        #pragma unroll
        for (int o = 0; o < 10; ++o) p[o] += xmove_swz_b4(p[o]);
        #pragma unroll
        for (int o = 0; o < 10; ++o) p[o] += xmove_dpp_b8(p[o]);
        float tot = p[0];
        #pragma unroll
        for (int o = 1; o < 10; ++o)
            tot = (hg == o) ? p[o] : tot;
        float cur2 = __fadd_rn(tot, b2r);
        float m2 = __fsub_rn(__fadd_rn(__fmul_rn(0.9f, mem2), cur2), spk2);
        mem2 = m2;
        spk2 = (m2 > 1.0f) ? 1.0f : 0.0f;
        if (hg < 10)
            out[(size_t)t * (NB * NO) + row * NO + hg] = spk2;
    }
}

extern "C" void kernel_launch(void* const* d_in, const int* in_sizes, int n_in,
                              void* d_out, int out_size, void* d_ws, size_t ws_size,
                              hipStream_t stream) {
    const float* data = (const float*)d_in[0];
    const float* W1   = (const float*)d_in[1];
    const float* b1   = (const float*)d_in[2];
    const float* W2   = (const float*)d_in[3];
    const float* b2   = (const float*)d_in[4];
    float* out  = (float*)d_out;

    // ws: cur1 [16384*128 f32] = 8388608 B, then Wt [784*128 f32] = 401408 B
    float* cur1 = (float*)d_ws;
    float* Wt   = (float*)((char*)d_ws + (size_t)NB * NH * 4);

    w1_transpose<<<ND, NH, 0, stream>>>(W1, Wt);
    gemm_cur1<<<512, 256, 0, stream>>>(data, Wt, b1, cur1);
    snn_loop<<<1024, 256, 0, stream>>>(cur1, W2, b2, out);
}